// Round 1
// baseline (969.229 us; speedup 1.0000x reference)
//
#include <hip/hip_runtime.h>
#include <math.h>

#define HW 4096
#define KTOT 2304   // 256 * 9

// ------------------------------------------------------------------
// ws layout (floats):
//   [0, 589824)        offset buffer  (8 x 18 x 64 x 64)
//   [589824, 1179648)  wT             (2304 x 256)
//   [1179648, 1180160) stats          (256 x float2 {mean, rstd})
// ------------------------------------------------------------------

__global__ __launch_bounds__(256) void k_transpose_w(const float* __restrict__ w,
                                                     float* __restrict__ wT) {
  int idx = blockIdx.x * 256 + threadIdx.x;   // 589824 total
  int oc = idx & 255;
  int kg = idx >> 8;                          // 0..2303
  wT[(size_t)kg * 256 + oc] = w[(size_t)oc * KTOT + kg];
}

__global__ __launch_bounds__(256) void k_offset_conv(
    const float* __restrict__ x, const float* __restrict__ w_off,
    const float* __restrict__ b_off, float* __restrict__ off_out) {
  int bid = blockIdx.x;            // n*64 + ho
  int n = bid >> 6, ho = bid & 63;
  int t = threadIdx.x;
  int wo = t & 63, cq = t >> 6;    // 4 channel-quarters
  float acc[18];
#pragma unroll
  for (int i = 0; i < 18; ++i) acc[i] = 0.f;
  const float* xb = x + ((size_t)n * 256) * HW;
  for (int c = cq * 64; c < cq * 64 + 64; ++c) {
    const float* xc = xb + (size_t)c * HW;
#pragma unroll
    for (int ky = 0; ky < 3; ++ky) {
      int y = ho + ky - 1;
      if (y >= 0 && y < 64) {
        const float* row = xc + y * 64;
        float v0 = (wo > 0)  ? row[wo - 1] : 0.f;
        float v1 = row[wo];
        float v2 = (wo < 63) ? row[wo + 1] : 0.f;
        const float* wp = w_off + c * 9 + ky * 3;   // + oc*2304, wave-uniform
#pragma unroll
        for (int oc = 0; oc < 18; ++oc) {
          const float* w3 = wp + oc * KTOT;
          acc[oc] += v0 * w3[0] + v1 * w3[1] + v2 * w3[2];
        }
      }
    }
  }
  __shared__ float red[4][18][64];   // 18.4 KB
#pragma unroll
  for (int oc = 0; oc < 18; ++oc) red[cq][oc][wo] = acc[oc];
  __syncthreads();
  for (int idx = t; idx < 18 * 64; idx += 256) {
    int oc = idx >> 6, w2 = idx & 63;
    float s = red[0][oc][w2] + red[1][oc][w2] + red[2][oc][w2] + red[3][oc][w2] +
              b_off[oc];
    off_out[(((size_t)n * 18 + oc) * 64 + ho) * 64 + w2] = s;
  }
}

// Deformable conv: block = (n, ho). Out tile 64 wo x 256 oc.
// Thread tile: 4 wo x 16 oc (wo4 = (t&15)*4, ocb = (t>>4)*16).
__global__ __launch_bounds__(256) void k_deform(
    const float* __restrict__ x, const float* __restrict__ off,
    const float* __restrict__ wT, float* __restrict__ out) {
  int bid = blockIdx.x;
  int n = bid >> 6, ho = bid & 63;
  int t = threadIdx.x;

  __shared__ int4   s_posA[576];     // iy0*64, iy1*64, ix0, ix1   (9.2 KB)
  __shared__ float4 s_posB[576];     // wtl, wtr, wbl, wbr         (9.2 KB)
  __shared__ float  s_val[144 * 64]; // 16c * 9kk  x 64 wo        (36.9 KB)

  // ---- phase 0: bilinear positions & weights (shared by all channels) ----
  for (int p = t; p < 576; p += 256) {
    int kk = p >> 6, wo = p & 63;
    int ky = kk / 3, kx = kk - ky * 3;
    const float* offp = off + (((size_t)n * 18 + 2 * kk) * 64 + ho) * 64 + wo;
    float dy = offp[0];
    float dx = offp[HW];             // next channel (+64*64)
    float py = (float)(ho - 1 + ky) + dy;
    float px = (float)(wo - 1 + kx) + dx;
    float y0f = floorf(py), x0f = floorf(px);
    float ly = py - y0f, lx = px - x0f;
    int y0 = (int)y0f, x0 = (int)x0f;
    int y1 = y0 + 1, x1 = x0 + 1;
    float vy0 = (y0 >= 0 && y0 < 64) ? 1.f : 0.f;
    float vy1 = (y1 >= 0 && y1 < 64) ? 1.f : 0.f;
    float vx0 = (x0 >= 0 && x0 < 64) ? 1.f : 0.f;
    float vx1 = (x1 >= 0 && x1 < 64) ? 1.f : 0.f;
    int iy0 = min(max(y0, 0), 63) * 64;
    int iy1 = min(max(y1, 0), 63) * 64;
    int ix0 = min(max(x0, 0), 63);
    int ix1 = min(max(x1, 0), 63);
    s_posA[p] = make_int4(iy0, iy1, ix0, ix1);
    s_posB[p] = make_float4((1.f - ly) * (1.f - lx) * vy0 * vx0,
                            (1.f - ly) * lx         * vy0 * vx1,
                            ly         * (1.f - lx) * vy1 * vx0,
                            ly         * lx         * vy1 * vx1);
  }
  __syncthreads();

  float acc[4][16];
#pragma unroll
  for (int i = 0; i < 4; ++i)
#pragma unroll
    for (int j = 0; j < 16; ++j) acc[i][j] = 0.f;

  int wo = t & 63, grp = t >> 6;
  int wo4 = (t & 15) * 4, ocb = (t >> 4) * 16;
  const float* xn = x + (size_t)n * 256 * HW;

  for (int c0 = 0; c0 < 256; c0 += 16) {
    // ---- gather: build val[16c*9kk][64wo] in LDS ----
#pragma unroll
    for (int cl = 0; cl < 4; ++cl) {
      int clc = grp * 4 + cl;            // c_local 0..15
      const float* xc = xn + (size_t)(c0 + clc) * HW;
#pragma unroll
      for (int kk = 0; kk < 9; ++kk) {
        int p = kk * 64 + wo;
        int4 A = s_posA[p];
        float4 B = s_posB[p];
        float v = B.x * xc[A.x + A.z] + B.y * xc[A.x + A.w] +
                  B.z * xc[A.y + A.z] + B.w * xc[A.y + A.w];
        s_val[(clc * 9 + kk) * 64 + wo] = v;
      }
    }
    __syncthreads();

    // ---- compute: 144 k-steps, 64 FMA each ----
    const float* wbase = wT + ((size_t)c0 * 9) * 256 + ocb;
#pragma unroll 2
    for (int kl = 0; kl < 144; ++kl) {
      float4 a4 = *(const float4*)&s_val[kl * 64 + wo4];
      const float* wr = wbase + (size_t)kl * 256;
      float4 w0 = *(const float4*)&wr[0];
      float4 w1 = *(const float4*)&wr[4];
      float4 w2 = *(const float4*)&wr[8];
      float4 w3 = *(const float4*)&wr[12];
      float av[4] = {a4.x, a4.y, a4.z, a4.w};
      float wv[16];
      *(float4*)&wv[0]  = w0;
      *(float4*)&wv[4]  = w1;
      *(float4*)&wv[8]  = w2;
      *(float4*)&wv[12] = w3;
#pragma unroll
      for (int i = 0; i < 4; ++i)
#pragma unroll
        for (int j = 0; j < 16; ++j) acc[i][j] += av[i] * wv[j];
    }
    __syncthreads();
  }

  // ---- epilogue: raw conv output to d_out ----
#pragma unroll
  for (int j = 0; j < 16; ++j) {
    int oc = ocb + j;
    float* op = out + (((size_t)n * 256 + oc) * 64 + ho) * 64 + wo4;
#pragma unroll
    for (int i = 0; i < 4; ++i) op[i] = acc[i][j];
  }
}

__global__ __launch_bounds__(256) void k_stats(const float* __restrict__ out,
                                               float2* __restrict__ stats) {
  int ch = blockIdx.x;
  int t = threadIdx.x;
  float s = 0.f, sq = 0.f;
  for (int n = 0; n < 8; ++n) {
    const float4* p = (const float4*)(out + ((size_t)n * 256 + ch) * HW);
    for (int i = t; i < 1024; i += 256) {
      float4 v = p[i];
      s += v.x + v.y + v.z + v.w;
      sq += v.x * v.x + v.y * v.y + v.z * v.z + v.w * v.w;
    }
  }
#pragma unroll
  for (int o = 32; o; o >>= 1) {
    s += __shfl_down(s, o);
    sq += __shfl_down(sq, o);
  }
  __shared__ float2 wsum[4];
  if ((t & 63) == 0) wsum[t >> 6] = make_float2(s, sq);
  __syncthreads();
  if (t == 0) {
    float S = wsum[0].x + wsum[1].x + wsum[2].x + wsum[3].x;
    float Q = wsum[0].y + wsum[1].y + wsum[2].y + wsum[3].y;
    float mean = S / 32768.f;
    float var = Q / 32768.f - mean * mean;
    stats[ch] = make_float2(mean, rsqrtf(var + 1e-5f));
  }
}

__global__ __launch_bounds__(256) void k_bn_silu(float* __restrict__ out,
                                                 const float2* __restrict__ stats,
                                                 const float* __restrict__ gamma,
                                                 const float* __restrict__ beta) {
  size_t i4 = (size_t)blockIdx.x * 256 + threadIdx.x;  // 2,097,152 total
  int ch = (int)((i4 >> 10) & 255);
  float2 st = stats[ch];
  float g = gamma[ch] * st.y;
  float b = beta[ch] - st.x * g;
  float4 v = *(float4*)(out + i4 * 4);
  float y0 = v.x * g + b, y1 = v.y * g + b, y2 = v.z * g + b, y3 = v.w * g + b;
  v.x = y0 / (1.f + expf(-y0));
  v.y = y1 / (1.f + expf(-y1));
  v.z = y2 / (1.f + expf(-y2));
  v.w = y3 / (1.f + expf(-y3));
  *(float4*)(out + i4 * 4) = v;
}

extern "C" void kernel_launch(void* const* d_in, const int* in_sizes, int n_in,
                              void* d_out, int out_size, void* d_ws, size_t ws_size,
                              hipStream_t stream) {
  const float* x      = (const float*)d_in[0];
  const float* w_off  = (const float*)d_in[1];
  const float* b_off  = (const float*)d_in[2];
  const float* w_conv = (const float*)d_in[3];
  const float* gamma  = (const float*)d_in[4];
  const float* beta   = (const float*)d_in[5];
  float* out = (float*)d_out;

  float* ws      = (float*)d_ws;
  float* ws_off  = ws;                 // 589824 floats
  float* ws_wT   = ws + 589824;        // 589824 floats
  float2* ws_st  = (float2*)(ws + 1179648);  // 256 float2

  k_transpose_w<<<2304, 256, 0, stream>>>(w_conv, ws_wT);
  k_offset_conv<<<512, 256, 0, stream>>>(x, w_off, b_off, ws_off);
  k_deform<<<512, 256, 0, stream>>>(x, ws_off, ws_wT, out);
  k_stats<<<256, 256, 0, stream>>>(out, ws_st);
  k_bn_silu<<<8192, 256, 0, stream>>>(out, ws_st, gamma, beta);
}

// Round 2
// 506.812 us; speedup vs baseline: 1.9124x; 1.9124x over previous
//
#include <hip/hip_runtime.h>
#include <math.h>

#define HW 4096
#define KTOT 2304   // 256 * 9

typedef __attribute__((ext_vector_type(8))) short short8v;
typedef __attribute__((ext_vector_type(4))) float float4v;

__device__ __forceinline__ unsigned int bf16rne(float f) {
  unsigned int x = __float_as_uint(f);
  return (x + 0x7fffu + ((x >> 16) & 1u)) >> 16;
}

// ------------------------------------------------------------------
// ws layout (floats):
//   [0, 589824)         offset buffer  (8 x 18 x 64 x 64)  f32
//   [589824, 1179648)   wBfrag         (72 ks x 16 of x 64 lane x 8) bf16
//   [1179648, 1180160)  stats          (256 x float2 {mean, rstd})
// ------------------------------------------------------------------

// Pack w_conv[oc][c][kk] (f32) into MFMA-A-fragment-native bf16 layout:
// wB[((ks*16 + of)*64 + l)*8 + j] = bf16(W[oc = of*16 + (l&15)][k = ks*32 + (l>>4)*8 + j])
// with k = kk*256 + c  (kk-major).
__global__ __launch_bounds__(256) void k_prep_b(const float* __restrict__ w,
                                                ushort* __restrict__ wB) {
  int t = blockIdx.x * 256 + threadIdx.x;   // 73728 total
  int ks = t >> 10;
  int l = t & 63;
  int of = (t >> 6) & 15;
  int kk = ks >> 3;
  int cbase = ((ks & 7) << 5) + ((l >> 4) << 3);
  int oc = (of << 4) + (l & 15);
  unsigned int u[8];
#pragma unroll
  for (int j = 0; j < 8; ++j)
    u[j] = bf16rne(w[(size_t)oc * KTOT + (size_t)(cbase + j) * 9 + kk]);
  uint4 o;
  o.x = u[0] | (u[1] << 16);
  o.y = u[2] | (u[3] << 16);
  o.z = u[4] | (u[5] << 16);
  o.w = u[6] | (u[7] << 16);
  *reinterpret_cast<uint4*>(&wB[(size_t)t * 8]) = o;
}

__global__ __launch_bounds__(256) void k_offset_conv(
    const float* __restrict__ x, const float* __restrict__ w_off,
    const float* __restrict__ b_off, float* __restrict__ off_out) {
  int bid = blockIdx.x;            // n*64 + ho
  int n = bid >> 6, ho = bid & 63;
  int t = threadIdx.x;
  int wo = t & 63, cq = t >> 6;    // 4 channel-quarters
  float acc[18];
#pragma unroll
  for (int i = 0; i < 18; ++i) acc[i] = 0.f;
  const float* xb = x + ((size_t)n * 256) * HW;
  for (int c = cq * 64; c < cq * 64 + 64; ++c) {
    const float* xc = xb + (size_t)c * HW;
#pragma unroll
    for (int ky = 0; ky < 3; ++ky) {
      int y = ho + ky - 1;
      if (y >= 0 && y < 64) {
        const float* row = xc + y * 64;
        float v0 = (wo > 0)  ? row[wo - 1] : 0.f;
        float v1 = row[wo];
        float v2 = (wo < 63) ? row[wo + 1] : 0.f;
        const float* wp = w_off + c * 9 + ky * 3;
#pragma unroll
        for (int oc = 0; oc < 18; ++oc) {
          const float* w3 = wp + oc * KTOT;
          acc[oc] += v0 * w3[0] + v1 * w3[1] + v2 * w3[2];
        }
      }
    }
  }
  __shared__ float red[4][18][64];
#pragma unroll
  for (int oc = 0; oc < 18; ++oc) red[cq][oc][wo] = acc[oc];
  __syncthreads();
  for (int idx = t; idx < 18 * 64; idx += 256) {
    int oc = idx >> 6, w2 = idx & 63;
    float s = red[0][oc][w2] + red[1][oc][w2] + red[2][oc][w2] + red[3][oc][w2] +
              b_off[oc];
    off_out[(((size_t)n * 18 + oc) * 64 + ho) * 64 + w2] = s;
  }
}

// ------------------------------------------------------------------
// Deformable conv as implicit GEMM via MFMA.
// Block: 128 pix (2 ho rows x 64 wo) x 256 oc. Grid 256 = (n 8) x (ho-pair 32).
// 256 threads = 4 waves; wave w owns oc [w*64, w*64+64), all 128 pix.
// Wave frags: 4 oc-frags (A, from global frag-native wB) x 8 pix-frags
// (B, from LDS val tile). acc[4][8] float4.
// K = kk*256 + c. 36 chunks of 64 c (9 kk x 4 c-quarters), 2 MFMA ksteps each.
// LDS val tile: [128 pix][64 c] bf16, 16B-block XOR swizzle: block' = blk ^ (pix&7).
// ------------------------------------------------------------------
__global__ __launch_bounds__(256, 1) void k_deform_mfma(
    const float* __restrict__ x, const float* __restrict__ off,
    const ushort* __restrict__ wB, float* __restrict__ out) {
  __shared__ ushort s_val[128 * 64];   // 16 KB

  int bid = blockIdx.x;
  int n = bid >> 5;
  int ho0 = (bid & 31) << 1;
  int t = threadIdx.x;
  int lane = t & 63;
  int wave = t >> 6;

  // gather mapping: thread -> (pix, 32 consecutive c within chunk)
  int pix_t = (((t >> 6) & 1) << 6) + lane;  // 0..127
  int chalf = t >> 7;                        // 0/1
  int pix7 = pix_t & 7;
  int ho_t = ho0 + (pix_t >> 6);
  int wo_t = pix_t & 63;

  float4v acc[4][8];
#pragma unroll
  for (int a = 0; a < 4; ++a)
#pragma unroll
    for (int b = 0; b < 8; ++b) acc[a][b] = (float4v)0.f;

  const float* xn = x + (size_t)n * 256 * HW;
  int wave4 = wave << 2;   // wave's oc-frag base index

  for (int kk = 0; kk < 9; ++kk) {
    // ---- per-kk bilinear position for this thread's pixel ----
    int ky = kk / 3, kx = kk - ky * 3;
    const float* offp = off + (((size_t)n * 18 + 2 * kk) * 64 + ho_t) * 64 + wo_t;
    float dy = offp[0];
    float dx = offp[HW];
    float py = (float)(ho_t - 1 + ky) + dy;
    float px = (float)(wo_t - 1 + kx) + dx;
    float y0f = floorf(py), x0f = floorf(px);
    float ly = py - y0f, lx = px - x0f;
    int y0 = (int)y0f, x0 = (int)x0f;
    int y1 = y0 + 1, x1 = x0 + 1;
    float vy0 = (y0 >= 0 && y0 < 64) ? 1.f : 0.f;
    float vy1 = (y1 >= 0 && y1 < 64) ? 1.f : 0.f;
    float vx0 = (x0 >= 0 && x0 < 64) ? 1.f : 0.f;
    float vx1 = (x1 >= 0 && x1 < 64) ? 1.f : 0.f;
    int o0 = min(max(y0, 0), 63) * 64 + min(max(x0, 0), 63);
    int o1 = min(max(y0, 0), 63) * 64 + min(max(x1, 0), 63);
    int o2 = min(max(y1, 0), 63) * 64 + min(max(x0, 0), 63);
    int o3 = min(max(y1, 0), 63) * 64 + min(max(x1, 0), 63);
    float w0 = (1.f - ly) * (1.f - lx) * vy0 * vx0;
    float w1 = (1.f - ly) * lx * vy0 * vx1;
    float w2 = ly * (1.f - lx) * vy1 * vx0;
    float w3 = ly * lx * vy1 * vx1;

    for (int cq = 0; cq < 4; ++cq) {
      int ch = (kk << 2) + cq;
      // ---- gather: 32 c values for this thread's pixel -> LDS (bf16) ----
      const float* xc = xn + ((size_t)(cq * 64 + chalf * 32) << 12);
#pragma unroll
      for (int ib = 0; ib < 4; ++ib) {
        unsigned int up[4];
#pragma unroll
        for (int p = 0; p < 4; ++p) {
          float a0 = xc[o0], a1 = xc[o1], a2 = xc[o2], a3 = xc[o3];
          const float* xc2 = xc + HW;
          float b0 = xc2[o0], b1 = xc2[o1], b2 = xc2[o2], b3 = xc2[o3];
          float v0 = w0 * a0 + w1 * a1 + w2 * a2 + w3 * a3;
          float v1 = w0 * b0 + w1 * b1 + w2 * b2 + w3 * b3;
          up[p] = bf16rne(v0) | (bf16rne(v1) << 16);
          xc += 2 * HW;
        }
        int slot = ((chalf << 2) + ib) ^ pix7;
        *reinterpret_cast<int4*>(&s_val[pix_t * 64 + slot * 8]) =
            make_int4(up[0], up[1], up[2], up[3]);
      }
      __syncthreads();

      // ---- MFMA: 2 ksteps over this 64-c chunk ----
#pragma unroll
      for (int ks2 = 0; ks2 < 2; ++ks2) {
        int ks = (ch << 1) + ks2;
        short8v wf[4];
#pragma unroll
        for (int mf = 0; mf < 4; ++mf)
          wf[mf] = *reinterpret_cast<const short8v*>(
              &wB[(((size_t)(ks * 16 + wave4 + mf)) * 64 + lane) * 8]);
#pragma unroll
        for (int pf = 0; pf < 8; ++pf) {
          int row = (pf << 4) + (lane & 15);
          int blk = (ks2 << 2) + (lane >> 4);
          int slot = blk ^ (row & 7);
          short8v vf = *reinterpret_cast<const short8v*>(&s_val[row * 64 + slot * 8]);
#pragma unroll
          for (int mf = 0; mf < 4; ++mf)
            acc[mf][pf] = __builtin_amdgcn_mfma_f32_16x16x32_bf16(
                wf[mf], vf, acc[mf][pf], 0, 0, 0);
        }
      }
      __syncthreads();
    }
  }

  // ---- epilogue: D[oc][pix] -> out[n][oc][ho][wo] ----
#pragma unroll
  for (int mf = 0; mf < 4; ++mf) {
    int oc = (wave << 6) + (mf << 4) + ((lane >> 4) << 2);
#pragma unroll
    for (int pf = 0; pf < 8; ++pf) {
      int pix = (pf << 4) + (lane & 15);
      int ho = ho0 + (pix >> 6), wo = pix & 63;
      float* op = out + (((size_t)(n * 256 + oc)) * 64 + ho) * 64 + wo;
      op[0] = acc[mf][pf][0];
      op[HW] = acc[mf][pf][1];
      op[2 * HW] = acc[mf][pf][2];
      op[3 * HW] = acc[mf][pf][3];
    }
  }
}

__global__ __launch_bounds__(256) void k_stats(const float* __restrict__ out,
                                               float2* __restrict__ stats) {
  int ch = blockIdx.x;
  int t = threadIdx.x;
  float s = 0.f, sq = 0.f;
  for (int n = 0; n < 8; ++n) {
    const float4* p = (const float4*)(out + ((size_t)n * 256 + ch) * HW);
    for (int i = t; i < 1024; i += 256) {
      float4 v = p[i];
      s += v.x + v.y + v.z + v.w;
      sq += v.x * v.x + v.y * v.y + v.z * v.z + v.w * v.w;
    }
  }
#pragma unroll
  for (int o = 32; o; o >>= 1) {
    s += __shfl_down(s, o);
    sq += __shfl_down(sq, o);
  }
  __shared__ float2 wsum[4];
  if ((t & 63) == 0) wsum[t >> 6] = make_float2(s, sq);
  __syncthreads();
  if (t == 0) {
    float S = wsum[0].x + wsum[1].x + wsum[2].x + wsum[3].x;
    float Q = wsum[0].y + wsum[1].y + wsum[2].y + wsum[3].y;
    float mean = S / 32768.f;
    float var = Q / 32768.f - mean * mean;
    stats[ch] = make_float2(mean, rsqrtf(var + 1e-5f));
  }
}

__global__ __launch_bounds__(256) void k_bn_silu(float* __restrict__ out,
                                                 const float2* __restrict__ stats,
                                                 const float* __restrict__ gamma,
                                                 const float* __restrict__ beta) {
  size_t i4 = (size_t)blockIdx.x * 256 + threadIdx.x;
  int ch = (int)((i4 >> 10) & 255);
  float2 st = stats[ch];
  float g = gamma[ch] * st.y;
  float b = beta[ch] - st.x * g;
  float4 v = *(float4*)(out + i4 * 4);
  float y0 = v.x * g + b, y1 = v.y * g + b, y2 = v.z * g + b, y3 = v.w * g + b;
  v.x = y0 / (1.f + expf(-y0));
  v.y = y1 / (1.f + expf(-y1));
  v.z = y2 / (1.f + expf(-y2));
  v.w = y3 / (1.f + expf(-y3));
  *(float4*)(out + i4 * 4) = v;
}

extern "C" void kernel_launch(void* const* d_in, const int* in_sizes, int n_in,
                              void* d_out, int out_size, void* d_ws, size_t ws_size,
                              hipStream_t stream) {
  const float* x      = (const float*)d_in[0];
  const float* w_off  = (const float*)d_in[1];
  const float* b_off  = (const float*)d_in[2];
  const float* w_conv = (const float*)d_in[3];
  const float* gamma  = (const float*)d_in[4];
  const float* beta   = (const float*)d_in[5];
  float* out = (float*)d_out;

  float* ws      = (float*)d_ws;
  float* ws_off  = ws;                          // 589824 f32
  ushort* ws_wB  = (ushort*)(ws + 589824);      // 1179648 bf16
  float2* ws_st  = (float2*)(ws + 1179648);     // 256 float2

  k_prep_b<<<288, 256, 0, stream>>>(w_conv, ws_wB);
  k_offset_conv<<<512, 256, 0, stream>>>(x, w_off, b_off, ws_off);
  k_deform_mfma<<<256, 256, 0, stream>>>(x, ws_off, ws_wB, out);
  k_stats<<<256, 256, 0, stream>>>(out, ws_st);
  k_bn_silu<<<8192, 256, 0, stream>>>(out, ws_st, gamma, beta);
}

// Round 3
// 200.109 us; speedup vs baseline: 4.8435x; 2.5327x over previous
//
#include <hip/hip_runtime.h>
#include <math.h>

#define HW 4096
#define KTOT 2304   // 256 * 9

typedef __attribute__((ext_vector_type(8))) short short8v;
typedef __attribute__((ext_vector_type(4))) float float4v;

__device__ __forceinline__ unsigned int bf16rne(float f) {
  unsigned int x = __float_as_uint(f);
  return (x + 0x7fffu + ((x >> 16) & 1u)) >> 16;
}

__device__ __forceinline__ unsigned int bilin_pack(unsigned int u0, unsigned int u1,
                                                   unsigned int u2, unsigned int u3,
                                                   float w0, float w1, float w2, float w3) {
  float lo = w0 * __uint_as_float(u0 << 16) + w1 * __uint_as_float(u1 << 16) +
             w2 * __uint_as_float(u2 << 16) + w3 * __uint_as_float(u3 << 16);
  float hi = w0 * __uint_as_float(u0 & 0xFFFF0000u) + w1 * __uint_as_float(u1 & 0xFFFF0000u) +
             w2 * __uint_as_float(u2 & 0xFFFF0000u) + w3 * __uint_as_float(u3 & 0xFFFF0000u);
  return bf16rne(lo) | (bf16rne(hi) << 16);
}

// ------------------------------------------------------------------
// ws layout (float offsets):
//   0        : off      [8][4096][18] f32            (589824 f)
//   589824   : xT       [8][4096][256] bf16          (4194304 f-equiv)
//   4784128  : wB       [72][16][64][8] bf16         (294912 f)
//   5079040  : wOffB    [72][2][64][8] bf16          (36864 f)
//   5115904  : part     [256 oc][512 blk] float2     (262144 f)
//   5378048  : stats    [256] float2                 (512 f)
// ------------------------------------------------------------------

// NCHW f32 -> NHWC bf16. Grid 512 (n x 64 pixgroups), 256 thr.
__global__ __launch_bounds__(256) void k_tx(const float* __restrict__ x,
                                            ushort* __restrict__ xT) {
  int bid = blockIdx.x;
  int n = bid >> 6, p0 = (bid & 63) << 6;
  int t = threadIdx.x;
  int lane = t & 63, wave = t >> 6, c0 = wave << 6;
  const float* xb = x + ((size_t)(n * 256 + c0)) * HW + p0 + lane;
  ushort* ob = xT + ((size_t)n * 4096 + p0 + lane) * 256 + c0;
#pragma unroll
  for (int g = 0; g < 8; ++g) {
    unsigned int u[4];
#pragma unroll
    for (int j = 0; j < 4; ++j) {
      float v0 = xb[(size_t)(g * 8 + 2 * j) * HW];
      float v1 = xb[(size_t)(g * 8 + 2 * j + 1) * HW];
      u[j] = bf16rne(v0) | (bf16rne(v1) << 16);
    }
    *reinterpret_cast<uint4*>(ob + g * 8) = make_uint4(u[0], u[1], u[2], u[3]);
  }
}

// w_conv -> A-fragment-native bf16: wB[((ks*16+of)*64+l)*8+j] =
//   W[oc=of*16+(l&15)][k=ks*32+(l>>4)*8+j], k = kk*256+c.
__global__ __launch_bounds__(256) void k_prep_b(const float* __restrict__ w,
                                                ushort* __restrict__ wB) {
  int t = blockIdx.x * 256 + threadIdx.x;   // 73728
  int ks = t >> 10;
  int l = t & 63;
  int of = (t >> 6) & 15;
  int kk = ks >> 3;
  int cbase = ((ks & 7) << 5) + ((l >> 4) << 3);
  int oc = (of << 4) + (l & 15);
  unsigned int u[8];
#pragma unroll
  for (int j = 0; j < 8; ++j)
    u[j] = bf16rne(w[(size_t)oc * KTOT + (size_t)(cbase + j) * 9 + kk]);
  *reinterpret_cast<uint4*>(&wB[(size_t)t * 8]) =
      make_uint4(u[0] | (u[1] << 16), u[2] | (u[3] << 16),
                 u[4] | (u[5] << 16), u[6] | (u[7] << 16));
}

// w_offset (18 oc, zero-pad to 32) -> frag layout wOffB[((ks*2+of)*64+l)*8+j]
__global__ __launch_bounds__(256) void k_prep_boff(const float* __restrict__ w,
                                                   ushort* __restrict__ wB) {
  int t = blockIdx.x * 256 + threadIdx.x;   // 9216
  int ks = t >> 7;
  int l = t & 63;
  int of = (t >> 6) & 1;
  int kk = ks >> 3;
  int cbase = ((ks & 7) << 5) + ((l >> 4) << 3);
  int oc = (of << 4) + (l & 15);
  unsigned int u[8];
#pragma unroll
  for (int j = 0; j < 8; ++j)
    u[j] = (oc < 18) ? bf16rne(w[(size_t)oc * KTOT + (size_t)(cbase + j) * 9 + kk]) : 0u;
  *reinterpret_cast<uint4*>(&wB[(size_t)t * 8]) =
      make_uint4(u[0] | (u[1] << 16), u[2] | (u[3] << 16),
                 u[4] | (u[5] << 16), u[6] | (u[7] << 16));
}

// Offset conv as implicit GEMM. Block: 128 pix x 32 oc (18 valid). Grid 256.
// 4 waves: (pixhalf = w&1, ochalf = w>>1). LDS tile [128 pix][64 c] bf16.
__global__ __launch_bounds__(256, 2) void k_offset_mfma(
    const ushort* __restrict__ xT, const ushort* __restrict__ wOffB,
    const float* __restrict__ b_off, float* __restrict__ off_out) {
  __shared__ ushort s_tile[128 * 64];   // 16 KB

  int bid = blockIdx.x;
  int n = bid >> 5;
  int pix0 = (bid & 31) << 7;
  int t = threadIdx.x;
  int lane = t & 63, wave = t >> 6;
  int p = t & 127, csub = t >> 7;       // gather: 2 thr/pix, 32 c each
  int gp = pix0 + p;
  int ho = gp >> 6, wo = gp & 63;
  int pixhalf = wave & 1, ochalf = wave >> 1;

  const ushort* xTn = xT + (size_t)n * 4096 * 256;

  float4v acc[4];
#pragma unroll
  for (int i = 0; i < 4; ++i) acc[i] = (float4v)0.f;

  for (int kk = 0; kk < 9; ++kk) {
    int ky = kk / 3, kx = kk - ky * 3;
    int oy = ho + ky - 1, ox = wo + kx - 1;
    bool valid = (oy >= 0) & (oy < 64) & (ox >= 0) & (ox < 64);
    const ushort* src = xTn + (size_t)(oy * 64 + ox) * 256;
    for (int cg = 0; cg < 4; ++cg) {
      int c0 = (cg << 6) + (csub << 5);
      uint4 v[2];
      if (valid) {
        v[0] = *reinterpret_cast<const uint4*>(src + c0);
        v[1] = *reinterpret_cast<const uint4*>(src + c0 + 8);
      } else {
        v[0] = make_uint4(0, 0, 0, 0);
        v[1] = make_uint4(0, 0, 0, 0);
      }
      uint4 v2[2];
      if (valid) {
        v2[0] = *reinterpret_cast<const uint4*>(src + c0 + 16);
        v2[1] = *reinterpret_cast<const uint4*>(src + c0 + 24);
      } else {
        v2[0] = make_uint4(0, 0, 0, 0);
        v2[1] = make_uint4(0, 0, 0, 0);
      }
#pragma unroll
      for (int i = 0; i < 2; ++i) {
        int slot = ((csub << 2) + i) ^ (p & 7);
        *reinterpret_cast<uint4*>(&s_tile[p * 64 + slot * 8]) = v[i];
      }
#pragma unroll
      for (int i = 0; i < 2; ++i) {
        int slot = ((csub << 2) + 2 + i) ^ (p & 7);
        *reinterpret_cast<uint4*>(&s_tile[p * 64 + slot * 8]) = v2[i];
      }
      __syncthreads();
#pragma unroll
      for (int ks2 = 0; ks2 < 2; ++ks2) {
        int ks = (kk << 3) + (cg << 1) + ks2;
        short8v wf = *reinterpret_cast<const short8v*>(
            &wOffB[(((size_t)(ks * 2 + ochalf)) * 64 + lane) * 8]);
#pragma unroll
        for (int pf = 0; pf < 4; ++pf) {
          int row = (pixhalf << 6) + (pf << 4) + (lane & 15);
          int g = (ks2 << 2) + (lane >> 4);
          int slot = g ^ (row & 7);
          short8v vf = *reinterpret_cast<const short8v*>(&s_tile[row * 64 + slot * 8]);
          acc[pf] = __builtin_amdgcn_mfma_f32_16x16x32_bf16(wf, vf, acc[pf], 0, 0, 0);
        }
      }
      __syncthreads();
    }
  }

  // epilogue: off_out[n][pix][18] = acc + bias
  int oc0 = (ochalf << 4) + ((lane >> 4) << 2);
#pragma unroll
  for (int pf = 0; pf < 4; ++pf) {
    int pixcol = (pixhalf << 6) + (pf << 4) + (lane & 15);
    size_t base = ((size_t)n * 4096 + pix0 + pixcol) * 18;
#pragma unroll
    for (int j = 0; j < 4; ++j) {
      int oc = oc0 + j;
      if (oc < 18) off_out[base + oc] = acc[pf][j] + b_off[oc];
    }
  }
}

// Deformable conv implicit GEMM. Block: 64 pix (1 ho row) x 256 oc. Grid 512.
// 4 waves by oc-quarter. LDS val tile [64 pix][64 c] bf16, XOR-swizzled.
__global__ __launch_bounds__(256, 2) void k_deform2(
    const ushort* __restrict__ xT, const float* __restrict__ off,
    const ushort* __restrict__ wB, float* __restrict__ out,
    float2* __restrict__ part) {
  __shared__ ushort s_val[64 * 64];   // 8 KB

  int bid = blockIdx.x;
  int n = bid >> 6, ho = bid & 63;
  int t = threadIdx.x;
  int lane = t & 63, wave = t >> 6;
  int p = t & 63, sub = t >> 6;       // gather: 4 thr/pix, 16 c each

  const ushort* xTn = xT + (size_t)n * 4096 * 256;
  const float* offb = off + ((size_t)n * 4096 + ho * 64 + p) * 18;

  float4v acc[4][4];
#pragma unroll
  for (int a = 0; a < 4; ++a)
#pragma unroll
    for (int b = 0; b < 4; ++b) acc[a][b] = (float4v)0.f;

  for (int kk = 0; kk < 9; ++kk) {
    int ky = kk / 3, kx = kk - ky * 3;
    float dy = offb[2 * kk];
    float dx = offb[2 * kk + 1];
    float py = (float)(ho - 1 + ky) + dy;
    float px = (float)(p - 1 + kx) + dx;
    float y0f = floorf(py), x0f = floorf(px);
    float ly = py - y0f, lx = px - x0f;
    int y0 = (int)y0f, x0 = (int)x0f;
    int y1 = y0 + 1, x1 = x0 + 1;
    float vy0 = (y0 >= 0 && y0 < 64) ? 1.f : 0.f;
    float vy1 = (y1 >= 0 && y1 < 64) ? 1.f : 0.f;
    float vx0 = (x0 >= 0 && x0 < 64) ? 1.f : 0.f;
    float vx1 = (x1 >= 0 && x1 < 64) ? 1.f : 0.f;
    int cy0 = min(max(y0, 0), 63) << 6, cy1 = min(max(y1, 0), 63) << 6;
    int cx0 = min(max(x0, 0), 63), cx1 = min(max(x1, 0), 63);
    const ushort* b0 = xTn + (size_t)(cy0 + cx0) * 256;
    const ushort* b1 = xTn + (size_t)(cy0 + cx1) * 256;
    const ushort* b2 = xTn + (size_t)(cy1 + cx0) * 256;
    const ushort* b3 = xTn + (size_t)(cy1 + cx1) * 256;
    float w0 = (1.f - ly) * (1.f - lx) * vy0 * vx0;
    float w1 = (1.f - ly) * lx * vy0 * vx1;
    float w2 = ly * (1.f - lx) * vy1 * vx0;
    float w3 = ly * lx * vy1 * vx1;

    for (int cg = 0; cg < 4; ++cg) {
      int c0 = (cg << 6) + (sub << 4);
      uint4 A0 = *reinterpret_cast<const uint4*>(b0 + c0);
      uint4 A1 = *reinterpret_cast<const uint4*>(b1 + c0);
      uint4 A2 = *reinterpret_cast<const uint4*>(b2 + c0);
      uint4 A3 = *reinterpret_cast<const uint4*>(b3 + c0);
      uint4 B0 = *reinterpret_cast<const uint4*>(b0 + c0 + 8);
      uint4 B1 = *reinterpret_cast<const uint4*>(b1 + c0 + 8);
      uint4 B2 = *reinterpret_cast<const uint4*>(b2 + c0 + 8);
      uint4 B3 = *reinterpret_cast<const uint4*>(b3 + c0 + 8);
      uint4 r0, r1;
      r0.x = bilin_pack(A0.x, A1.x, A2.x, A3.x, w0, w1, w2, w3);
      r0.y = bilin_pack(A0.y, A1.y, A2.y, A3.y, w0, w1, w2, w3);
      r0.z = bilin_pack(A0.z, A1.z, A2.z, A3.z, w0, w1, w2, w3);
      r0.w = bilin_pack(A0.w, A1.w, A2.w, A3.w, w0, w1, w2, w3);
      r1.x = bilin_pack(B0.x, B1.x, B2.x, B3.x, w0, w1, w2, w3);
      r1.y = bilin_pack(B0.y, B1.y, B2.y, B3.y, w0, w1, w2, w3);
      r1.z = bilin_pack(B0.z, B1.z, B2.z, B3.z, w0, w1, w2, w3);
      r1.w = bilin_pack(B0.w, B1.w, B2.w, B3.w, w0, w1, w2, w3);
      int slot0 = ((sub << 1)) ^ (p & 7);
      int slot1 = ((sub << 1) + 1) ^ (p & 7);
      *reinterpret_cast<uint4*>(&s_val[p * 64 + slot0 * 8]) = r0;
      *reinterpret_cast<uint4*>(&s_val[p * 64 + slot1 * 8]) = r1;
      __syncthreads();

#pragma unroll
      for (int ks2 = 0; ks2 < 2; ++ks2) {
        int ks = (kk << 3) + (cg << 1) + ks2;
        short8v wf[4];
#pragma unroll
        for (int mf = 0; mf < 4; ++mf)
          wf[mf] = *reinterpret_cast<const short8v*>(
              &wB[(((size_t)(ks * 16 + (wave << 2) + mf)) * 64 + lane) * 8]);
#pragma unroll
        for (int pf = 0; pf < 4; ++pf) {
          int row = (pf << 4) + (lane & 15);
          int g = (ks2 << 2) + (lane >> 4);
          int slot = g ^ (row & 7);
          short8v vf = *reinterpret_cast<const short8v*>(&s_val[row * 64 + slot * 8]);
#pragma unroll
          for (int mf = 0; mf < 4; ++mf)
            acc[mf][pf] = __builtin_amdgcn_mfma_f32_16x16x32_bf16(
                wf[mf], vf, acc[mf][pf], 0, 0, 0);
        }
      }
      __syncthreads();
    }
  }

  // ---- epilogue: out NCHW + per-block BN partials ----
#pragma unroll
  for (int mf = 0; mf < 4; ++mf) {
    int ocb = (wave << 6) + (mf << 4) + ((lane >> 4) << 2);
#pragma unroll
    for (int pf = 0; pf < 4; ++pf) {
      int wo = (pf << 4) + (lane & 15);
      float* op = out + (((size_t)(n * 256 + ocb)) * 64 + ho) * 64 + wo;
      float4v a = acc[mf][pf];
      op[0] = a[0];
      op[HW] = a[1];
      op[2 * HW] = a[2];
      op[3 * HW] = a[3];
    }
  }
  float s[4][4], q[4][4];
#pragma unroll
  for (int mf = 0; mf < 4; ++mf)
#pragma unroll
    for (int j = 0; j < 4; ++j) {
      float ss = 0.f, qq = 0.f;
#pragma unroll
      for (int pf = 0; pf < 4; ++pf) {
        float v = acc[mf][pf][j];
        ss += v;
        qq += v * v;
      }
      s[mf][j] = ss;
      q[mf][j] = qq;
    }
#pragma unroll
  for (int o = 1; o < 16; o <<= 1) {
#pragma unroll
    for (int mf = 0; mf < 4; ++mf)
#pragma unroll
      for (int j = 0; j < 4; ++j) {
        s[mf][j] += __shfl_xor(s[mf][j], o);
        q[mf][j] += __shfl_xor(q[mf][j], o);
      }
  }
  if ((lane & 15) == 0) {
#pragma unroll
    for (int mf = 0; mf < 4; ++mf)
#pragma unroll
      for (int j = 0; j < 4; ++j) {
        int oc = (wave << 6) + (mf << 4) + ((lane >> 4) << 2) + j;
        part[(size_t)oc * 512 + bid] = make_float2(s[mf][j], q[mf][j]);
      }
  }
}

__global__ __launch_bounds__(256) void k_stats_fin(const float2* __restrict__ part,
                                                   float2* __restrict__ stats) {
  int oc = blockIdx.x;
  int t = threadIdx.x;
  float2 a = part[(size_t)oc * 512 + t];
  float2 b = part[(size_t)oc * 512 + 256 + t];
  float s = a.x + b.x, q = a.y + b.y;
#pragma unroll
  for (int o = 32; o; o >>= 1) {
    s += __shfl_down(s, o);
    q += __shfl_down(q, o);
  }
  __shared__ float2 wsum[4];
  if ((t & 63) == 0) wsum[t >> 6] = make_float2(s, q);
  __syncthreads();
  if (t == 0) {
    float S = wsum[0].x + wsum[1].x + wsum[2].x + wsum[3].x;
    float Q = wsum[0].y + wsum[1].y + wsum[2].y + wsum[3].y;
    float mean = S / 32768.f;
    float var = Q / 32768.f - mean * mean;
    stats[oc] = make_float2(mean, rsqrtf(var + 1e-5f));
  }
}

__global__ __launch_bounds__(256) void k_bn_silu(float* __restrict__ out,
                                                 const float2* __restrict__ stats,
                                                 const float* __restrict__ gamma,
                                                 const float* __restrict__ beta) {
  size_t i4 = (size_t)blockIdx.x * 256 + threadIdx.x;
  int ch = (int)((i4 >> 10) & 255);
  float2 st = stats[ch];
  float g = gamma[ch] * st.y;
  float b = beta[ch] - st.x * g;
  float4 v = *(float4*)(out + i4 * 4);
  float y0 = v.x * g + b, y1 = v.y * g + b, y2 = v.z * g + b, y3 = v.w * g + b;
  v.x = y0 / (1.f + expf(-y0));
  v.y = y1 / (1.f + expf(-y1));
  v.z = y2 / (1.f + expf(-y2));
  v.w = y3 / (1.f + expf(-y3));
  *(float4*)(out + i4 * 4) = v;
}

extern "C" void kernel_launch(void* const* d_in, const int* in_sizes, int n_in,
                              void* d_out, int out_size, void* d_ws, size_t ws_size,
                              hipStream_t stream) {
  const float* x      = (const float*)d_in[0];
  const float* w_off  = (const float*)d_in[1];
  const float* b_off  = (const float*)d_in[2];
  const float* w_conv = (const float*)d_in[3];
  const float* gamma  = (const float*)d_in[4];
  const float* beta   = (const float*)d_in[5];
  float* out = (float*)d_out;

  float* ws       = (float*)d_ws;
  float*  ws_off  = ws;                               // [8][4096][18] f32
  ushort* ws_xT   = (ushort*)(ws + 589824);           // [8][4096][256] bf16
  ushort* ws_wB   = (ushort*)(ws + 4784128);          // deform weight frags
  ushort* ws_wOB  = (ushort*)(ws + 5079040);          // offset weight frags
  float2* ws_part = (float2*)(ws + 5115904);          // [256][512] partials
  float2* ws_st   = (float2*)(ws + 5378048);          // [256] stats

  k_tx<<<512, 256, 0, stream>>>(x, ws_xT);
  k_prep_b<<<288, 256, 0, stream>>>(w_conv, ws_wB);
  k_prep_boff<<<36, 256, 0, stream>>>(w_off, ws_wOB);
  k_offset_mfma<<<256, 256, 0, stream>>>(ws_xT, ws_wOB, b_off, ws_off);
  k_deform2<<<512, 256, 0, stream>>>(ws_xT, ws_off, ws_wB, out, ws_part);
  k_stats_fin<<<256, 256, 0, stream>>>(ws_part, ws_st);
  k_bn_silu<<<8192, 256, 0, stream>>>(out, ws_st, gamma, beta);
}

// Round 4
// 163.586 us; speedup vs baseline: 5.9249x; 1.2233x over previous
//
#include <hip/hip_runtime.h>
#include <math.h>

#define HW 4096
#define KTOT 2304   // 256 * 9

typedef __attribute__((ext_vector_type(8))) short short8v;
typedef __attribute__((ext_vector_type(4))) float float4v;

__device__ __forceinline__ unsigned int bf16rne(float f) {
  unsigned int x = __float_as_uint(f);
  return (x + 0x7fffu + ((x >> 16) & 1u)) >> 16;
}

__device__ __forceinline__ unsigned int bilin_pack(unsigned int u0, unsigned int u1,
                                                   unsigned int u2, unsigned int u3,
                                                   float w0, float w1, float w2, float w3) {
  float lo = w0 * __uint_as_float(u0 << 16) + w1 * __uint_as_float(u1 << 16) +
             w2 * __uint_as_float(u2 << 16) + w3 * __uint_as_float(u3 << 16);
  float hi = w0 * __uint_as_float(u0 & 0xFFFF0000u) + w1 * __uint_as_float(u1 & 0xFFFF0000u) +
             w2 * __uint_as_float(u2 & 0xFFFF0000u) + w3 * __uint_as_float(u3 & 0xFFFF0000u);
  return bf16rne(lo) | (bf16rne(hi) << 16);
}

// ------------------------------------------------------------------
// ws layout (float offsets):
//   0        : off      [8][4096][18] f32
//   589824   : xT       [8][4096][256] bf16
//   4784128  : wB       [72][16][64][8] bf16
//   5079040  : wOffB    [72][2][64][8] bf16
//   5115904  : part     [256 oc][512 blk] float2
//   5378048  : stats    [256] float2
// ------------------------------------------------------------------

// NCHW f32 -> NHWC bf16. Grid 512; n = bid&7 so image n stays on XCD n.
__global__ __launch_bounds__(256) void k_tx(const float* __restrict__ x,
                                            ushort* __restrict__ xT) {
  int bid = blockIdx.x;
  int n = bid & 7, p0 = (bid >> 3) << 6;
  int t = threadIdx.x;
  int lane = t & 63, wave = t >> 6, c0 = wave << 6;
  const float* xb = x + ((size_t)(n * 256 + c0)) * HW + p0 + lane;
  ushort* ob = xT + ((size_t)n * 4096 + p0 + lane) * 256 + c0;
#pragma unroll
  for (int g = 0; g < 8; ++g) {
    unsigned int u[4];
#pragma unroll
    for (int j = 0; j < 4; ++j) {
      float v0 = xb[(size_t)(g * 8 + 2 * j) * HW];
      float v1 = xb[(size_t)(g * 8 + 2 * j + 1) * HW];
      u[j] = bf16rne(v0) | (bf16rne(v1) << 16);
    }
    *reinterpret_cast<uint4*>(ob + g * 8) = make_uint4(u[0], u[1], u[2], u[3]);
  }
}

// w_conv -> A-fragment-native bf16.
__global__ __launch_bounds__(256) void k_prep_b(const float* __restrict__ w,
                                                ushort* __restrict__ wB) {
  int t = blockIdx.x * 256 + threadIdx.x;   // 73728
  int ks = t >> 10;
  int l = t & 63;
  int of = (t >> 6) & 15;
  int kk = ks >> 3;
  int cbase = ((ks & 7) << 5) + ((l >> 4) << 3);
  int oc = (of << 4) + (l & 15);
  unsigned int u[8];
#pragma unroll
  for (int j = 0; j < 8; ++j)
    u[j] = bf16rne(w[(size_t)oc * KTOT + (size_t)(cbase + j) * 9 + kk]);
  *reinterpret_cast<uint4*>(&wB[(size_t)t * 8]) =
      make_uint4(u[0] | (u[1] << 16), u[2] | (u[3] << 16),
                 u[4] | (u[5] << 16), u[6] | (u[7] << 16));
}

__global__ __launch_bounds__(256) void k_prep_boff(const float* __restrict__ w,
                                                   ushort* __restrict__ wB) {
  int t = blockIdx.x * 256 + threadIdx.x;   // 9216
  int ks = t >> 7;
  int l = t & 63;
  int of = (t >> 6) & 1;
  int kk = ks >> 3;
  int cbase = ((ks & 7) << 5) + ((l >> 4) << 3);
  int oc = (of << 4) + (l & 15);
  unsigned int u[8];
#pragma unroll
  for (int j = 0; j < 8; ++j)
    u[j] = (oc < 18) ? bf16rne(w[(size_t)oc * KTOT + (size_t)(cbase + j) * 9 + kk]) : 0u;
  *reinterpret_cast<uint4*>(&wB[(size_t)t * 8]) =
      make_uint4(u[0] | (u[1] << 16), u[2] | (u[3] << 16),
                 u[4] | (u[5] << 16), u[6] | (u[7] << 16));
}

// Offset conv implicit GEMM. Block: 64 pix (1 row) x 32 oc. Grid 512, n = bid&7.
// Wave w owns pix-frag pf=w, both oc-frags. LDS tile [64 pix][64 c].
__global__ __launch_bounds__(256, 2) void k_offset2(
    const ushort* __restrict__ xT, const ushort* __restrict__ wOffB,
    const float* __restrict__ b_off, float* __restrict__ off_out) {
  __shared__ ushort s_tile[64 * 64];   // 8 KB

  int bid = blockIdx.x;
  int n = bid & 7, ho = bid >> 3;
  int t = threadIdx.x;
  int lane = t & 63, wave = t >> 6;
  int p = t & 63, sub = t >> 6;

  const ushort* xTn = xT + (size_t)n * 4096 * 256;

  float4v acc[2];
  acc[0] = (float4v)0.f;
  acc[1] = (float4v)0.f;

  for (int kk = 0; kk < 9; ++kk) {
    int ky = kk / 3, kx = kk - ky * 3;
    int oy = ho + ky - 1, ox = p + kx - 1;
    bool valid = (oy >= 0) & (oy < 64) & (ox >= 0) & (ox < 64);
    const ushort* src = xTn + (size_t)(oy * 64 + ox) * 256;
#pragma unroll
    for (int cg = 0; cg < 4; ++cg) {
      int c0 = (cg << 6) + (sub << 4);
      uint4 v0 = make_uint4(0, 0, 0, 0), v1 = make_uint4(0, 0, 0, 0);
      if (valid) {
        v0 = *reinterpret_cast<const uint4*>(src + c0);
        v1 = *reinterpret_cast<const uint4*>(src + c0 + 8);
      }
      int slot0 = (sub << 1) ^ (p & 7);
      int slot1 = ((sub << 1) + 1) ^ (p & 7);
      *reinterpret_cast<uint4*>(&s_tile[p * 64 + slot0 * 8]) = v0;
      *reinterpret_cast<uint4*>(&s_tile[p * 64 + slot1 * 8]) = v1;
      __syncthreads();
#pragma unroll
      for (int ks2 = 0; ks2 < 2; ++ks2) {
        int ks = (kk << 3) + (cg << 1) + ks2;
        short8v wf0 = *reinterpret_cast<const short8v*>(
            &wOffB[(((size_t)(ks * 2 + 0)) * 64 + lane) * 8]);
        short8v wf1 = *reinterpret_cast<const short8v*>(
            &wOffB[(((size_t)(ks * 2 + 1)) * 64 + lane) * 8]);
        int row = (wave << 4) + (lane & 15);
        int g = (ks2 << 2) + (lane >> 4);
        int slot = g ^ (row & 7);
        short8v vf = *reinterpret_cast<const short8v*>(&s_tile[row * 64 + slot * 8]);
        acc[0] = __builtin_amdgcn_mfma_f32_16x16x32_bf16(wf0, vf, acc[0], 0, 0, 0);
        acc[1] = __builtin_amdgcn_mfma_f32_16x16x32_bf16(wf1, vf, acc[1], 0, 0, 0);
      }
      __syncthreads();
    }
  }

  int pixcol = (wave << 4) + (lane & 15);
  size_t base = ((size_t)n * 4096 + ho * 64 + pixcol) * 18;
#pragma unroll
  for (int of = 0; of < 2; ++of)
#pragma unroll
    for (int j = 0; j < 4; ++j) {
      int oc = (of << 4) + ((lane >> 4) << 2) + j;
      if (oc < 18) off_out[base + oc] = acc[of][j] + b_off[oc];
    }
}

// Deformable conv implicit GEMM. Block: 64 pix x 256 oc. Grid 512, n = bid&7.
// Geometry precomputed in LDS; tap loads ping-pong prefetched 1 chunk ahead.
__global__ __launch_bounds__(256, 2) void k_deform2(
    const ushort* __restrict__ xT, const float* __restrict__ off,
    const ushort* __restrict__ wB, float* __restrict__ out,
    float2* __restrict__ part) {
  __shared__ ushort s_val[64 * 64];   // 8 KB
  __shared__ int4   s_gi[9][64];      // 9.2 KB
  __shared__ float4 s_gw[9][64];      // 9.2 KB

  int bid = blockIdx.x;
  int n = bid & 7, ho = bid >> 3;
  int t = threadIdx.x;
  int lane = t & 63, wave = t >> 6;
  int p = t & 63, sub = t >> 6;

  const ushort* xTn = xT + (size_t)n * 4096 * 256;

  // ---- phase 0: bilinear geometry for all (kk, pix) ----
  for (int e = t; e < 576; e += 256) {
    int pix = e & 63, kk = e >> 6;
    int ky = kk / 3, kx = kk - ky * 3;
    const float* ob = off + ((size_t)n * 4096 + ho * 64 + pix) * 18;
    float dy = ob[2 * kk], dx = ob[2 * kk + 1];
    float py = (float)(ho - 1 + ky) + dy;
    float px = (float)(pix - 1 + kx) + dx;
    float y0f = floorf(py), x0f = floorf(px);
    float ly = py - y0f, lx = px - x0f;
    int y0 = (int)y0f, x0 = (int)x0f;
    int y1 = y0 + 1, x1 = x0 + 1;
    float vy0 = (y0 >= 0 && y0 < 64) ? 1.f : 0.f;
    float vy1 = (y1 >= 0 && y1 < 64) ? 1.f : 0.f;
    float vx0 = (x0 >= 0 && x0 < 64) ? 1.f : 0.f;
    float vx1 = (x1 >= 0 && x1 < 64) ? 1.f : 0.f;
    int cy0 = min(max(y0, 0), 63) << 6, cy1 = min(max(y1, 0), 63) << 6;
    int cx0 = min(max(x0, 0), 63), cx1 = min(max(x1, 0), 63);
    s_gi[kk][pix] = make_int4((cy0 + cx0) << 8, (cy0 + cx1) << 8,
                              (cy1 + cx0) << 8, (cy1 + cx1) << 8);
    s_gw[kk][pix] = make_float4((1.f - ly) * (1.f - lx) * vy0 * vx0,
                                (1.f - ly) * lx * vy0 * vx1,
                                ly * (1.f - lx) * vy1 * vx0,
                                ly * lx * vy1 * vx1);
  }
  __syncthreads();

  float4v acc[4][4];
#pragma unroll
  for (int a = 0; a < 4; ++a)
#pragma unroll
    for (int b = 0; b < 4; ++b) acc[a][b] = (float4v)0.f;

  uint4 LA[8], LB[8];
  int cbase = sub << 4;

  auto issue = [&](uint4 (&L)[8], const int4& g, int c0) {
    const ushort* p0 = xTn + g.x + c0;
    const ushort* p1 = xTn + g.y + c0;
    const ushort* p2 = xTn + g.z + c0;
    const ushort* p3 = xTn + g.w + c0;
    L[0] = *reinterpret_cast<const uint4*>(p0);
    L[1] = *reinterpret_cast<const uint4*>(p0 + 8);
    L[2] = *reinterpret_cast<const uint4*>(p1);
    L[3] = *reinterpret_cast<const uint4*>(p1 + 8);
    L[4] = *reinterpret_cast<const uint4*>(p2);
    L[5] = *reinterpret_cast<const uint4*>(p2 + 8);
    L[6] = *reinterpret_cast<const uint4*>(p3);
    L[7] = *reinterpret_cast<const uint4*>(p3 + 8);
  };

  auto consume = [&](uint4 (&L)[8], const float4& w, int ks0) {
    uint4 r0, r1;
    r0.x = bilin_pack(L[0].x, L[2].x, L[4].x, L[6].x, w.x, w.y, w.z, w.w);
    r0.y = bilin_pack(L[0].y, L[2].y, L[4].y, L[6].y, w.x, w.y, w.z, w.w);
    r0.z = bilin_pack(L[0].z, L[2].z, L[4].z, L[6].z, w.x, w.y, w.z, w.w);
    r0.w = bilin_pack(L[0].w, L[2].w, L[4].w, L[6].w, w.x, w.y, w.z, w.w);
    r1.x = bilin_pack(L[1].x, L[3].x, L[5].x, L[7].x, w.x, w.y, w.z, w.w);
    r1.y = bilin_pack(L[1].y, L[3].y, L[5].y, L[7].y, w.x, w.y, w.z, w.w);
    r1.z = bilin_pack(L[1].z, L[3].z, L[5].z, L[7].z, w.x, w.y, w.z, w.w);
    r1.w = bilin_pack(L[1].w, L[3].w, L[5].w, L[7].w, w.x, w.y, w.z, w.w);
    int slot0 = (sub << 1) ^ (p & 7);
    int slot1 = ((sub << 1) + 1) ^ (p & 7);
    *reinterpret_cast<uint4*>(&s_val[p * 64 + slot0 * 8]) = r0;
    *reinterpret_cast<uint4*>(&s_val[p * 64 + slot1 * 8]) = r1;
    asm volatile("s_waitcnt lgkmcnt(0)" ::: "memory");
    __builtin_amdgcn_s_barrier();
#pragma unroll
    for (int ks2 = 0; ks2 < 2; ++ks2) {
      int ks = ks0 + ks2;
      short8v wf[4];
#pragma unroll
      for (int mf = 0; mf < 4; ++mf)
        wf[mf] = *reinterpret_cast<const short8v*>(
            &wB[(((size_t)(ks * 16 + (wave << 2) + mf)) * 64 + lane) * 8]);
#pragma unroll
      for (int pf = 0; pf < 4; ++pf) {
        int row = (pf << 4) + (lane & 15);
        int g = (ks2 << 2) + (lane >> 4);
        int slot = g ^ (row & 7);
        short8v vf = *reinterpret_cast<const short8v*>(&s_val[row * 64 + slot * 8]);
#pragma unroll
        for (int mf = 0; mf < 4; ++mf)
          acc[mf][pf] = __builtin_amdgcn_mfma_f32_16x16x32_bf16(
              wf[mf], vf, acc[mf][pf], 0, 0, 0);
      }
    }
    __builtin_amdgcn_sched_barrier(0);
    __builtin_amdgcn_s_barrier();
  };

  int4 gi = s_gi[0][p];
  float4 gw = s_gw[0][p];
  issue(LA, gi, cbase);

  for (int kk = 0; kk < 9; ++kk) {
    int ks0 = kk << 3;
    issue(LB, gi, 64 + cbase);
    consume(LA, gw, ks0 + 0);
    issue(LA, gi, 128 + cbase);
    consume(LB, gw, ks0 + 2);
    issue(LB, gi, 192 + cbase);
    consume(LA, gw, ks0 + 4);
    int4 gin = gi;
    float4 gwn = gw;
    if (kk < 8) {
      gin = s_gi[kk + 1][p];
      gwn = s_gw[kk + 1][p];
      issue(LA, gin, cbase);
    }
    consume(LB, gw, ks0 + 6);
    gi = gin;
    gw = gwn;
  }

  // ---- epilogue: out NCHW + per-block BN partials ----
#pragma unroll
  for (int mf = 0; mf < 4; ++mf) {
    int ocb = (wave << 6) + (mf << 4) + ((lane >> 4) << 2);
#pragma unroll
    for (int pf = 0; pf < 4; ++pf) {
      int wo = (pf << 4) + (lane & 15);
      float* op = out + (((size_t)(n * 256 + ocb)) * 64 + ho) * 64 + wo;
      float4v a = acc[mf][pf];
      op[0] = a[0];
      op[HW] = a[1];
      op[2 * HW] = a[2];
      op[3 * HW] = a[3];
    }
  }
  float s[4][4], q[4][4];
#pragma unroll
  for (int mf = 0; mf < 4; ++mf)
#pragma unroll
    for (int j = 0; j < 4; ++j) {
      float ss = 0.f, qq = 0.f;
#pragma unroll
      for (int pf = 0; pf < 4; ++pf) {
        float v = acc[mf][pf][j];
        ss += v;
        qq += v * v;
      }
      s[mf][j] = ss;
      q[mf][j] = qq;
    }
#pragma unroll
  for (int o = 1; o < 16; o <<= 1) {
#pragma unroll
    for (int mf = 0; mf < 4; ++mf)
#pragma unroll
      for (int j = 0; j < 4; ++j) {
        s[mf][j] += __shfl_xor(s[mf][j], o);
        q[mf][j] += __shfl_xor(q[mf][j], o);
      }
  }
  if ((lane & 15) == 0) {
#pragma unroll
    for (int mf = 0; mf < 4; ++mf)
#pragma unroll
      for (int j = 0; j < 4; ++j) {
        int oc = (wave << 6) + (mf << 4) + ((lane >> 4) << 2) + j;
        part[(size_t)oc * 512 + bid] = make_float2(s[mf][j], q[mf][j]);
      }
  }
}

__global__ __launch_bounds__(256) void k_stats_fin(const float2* __restrict__ part,
                                                   float2* __restrict__ stats) {
  int oc = blockIdx.x;
  int t = threadIdx.x;
  float2 a = part[(size_t)oc * 512 + t];
  float2 b = part[(size_t)oc * 512 + 256 + t];
  float s = a.x + b.x, q = a.y + b.y;
#pragma unroll
  for (int o = 32; o; o >>= 1) {
    s += __shfl_down(s, o);
    q += __shfl_down(q, o);
  }
  __shared__ float2 wsum[4];
  if ((t & 63) == 0) wsum[t >> 6] = make_float2(s, q);
  __syncthreads();
  if (t == 0) {
    float S = wsum[0].x + wsum[1].x + wsum[2].x + wsum[3].x;
    float Q = wsum[0].y + wsum[1].y + wsum[2].y + wsum[3].y;
    float mean = S / 32768.f;
    float var = Q / 32768.f - mean * mean;
    stats[oc] = make_float2(mean, rsqrtf(var + 1e-5f));
  }
}

__global__ __launch_bounds__(256) void k_bn_silu(float* __restrict__ out,
                                                 const float2* __restrict__ stats,
                                                 const float* __restrict__ gamma,
                                                 const float* __restrict__ beta) {
  size_t i4 = (size_t)blockIdx.x * 256 + threadIdx.x;
  int ch = (int)((i4 >> 10) & 255);
  float2 st = stats[ch];
  float g = gamma[ch] * st.y;
  float b = beta[ch] - st.x * g;
  float4 v = *(float4*)(out + i4 * 4);
  float y0 = v.x * g + b, y1 = v.y * g + b, y2 = v.z * g + b, y3 = v.w * g + b;
  v.x = y0 / (1.f + expf(-y0));
  v.y = y1 / (1.f + expf(-y1));
  v.z = y2 / (1.f + expf(-y2));
  v.w = y3 / (1.f + expf(-y3));
  *(float4*)(out + i4 * 4) = v;
}

extern "C" void kernel_launch(void* const* d_in, const int* in_sizes, int n_in,
                              void* d_out, int out_size, void* d_ws, size_t ws_size,
                              hipStream_t stream) {
  const float* x      = (const float*)d_in[0];
  const float* w_off  = (const float*)d_in[1];
  const float* b_off  = (const float*)d_in[2];
  const float* w_conv = (const float*)d_in[3];
  const float* gamma  = (const float*)d_in[4];
  const float* beta   = (const float*)d_in[5];
  float* out = (float*)d_out;

  float* ws       = (float*)d_ws;
  float*  ws_off  = ws;                               // [8][4096][18] f32
  ushort* ws_xT   = (ushort*)(ws + 589824);           // [8][4096][256] bf16
  ushort* ws_wB   = (ushort*)(ws + 4784128);          // deform weight frags
  ushort* ws_wOB  = (ushort*)(ws + 5079040);          // offset weight frags
  float2* ws_part = (float2*)(ws + 5115904);          // [256][512] partials
  float2* ws_st   = (float2*)(ws + 5378048);          // [256] stats

  k_tx<<<512, 256, 0, stream>>>(x, ws_xT);
  k_prep_b<<<288, 256, 0, stream>>>(w_conv, ws_wB);
  k_prep_boff<<<36, 256, 0, stream>>>(w_off, ws_wOB);
  k_offset2<<<512, 256, 0, stream>>>(ws_xT, ws_wOB, b_off, ws_off);
  k_deform2<<<512, 256, 0, stream>>>(ws_xT, ws_off, ws_wB, out, ws_part);
  k_stats_fin<<<256, 256, 0, stream>>>(ws_part, ws_st);
  k_bn_silu<<<8192, 256, 0, stream>>>(out, ws_st, gamma, beta);
}